// Round 11
// baseline (189.481 us; speedup 1.0000x reference)
//
#include <hip/hip_runtime.h>

typedef _Float16 f16;
typedef __fp16 fp16x2 __attribute__((ext_vector_type(2)));
typedef _Float16 f16x8 __attribute__((ext_vector_type(8)));
typedef float f32x4 __attribute__((ext_vector_type(4)));
typedef float f32x16 __attribute__((ext_vector_type(16)));

#define AS1 __attribute__((address_space(1)))
#define AS3 __attribute__((address_space(3)))

#define SCALE_L2E 0.18033688011112042f   // 0.125 * log2(e), folded into Q

// ---- helpers ---------------------------------------------------------------

__device__ __forceinline__ void gload16(const void* g, void* l) {
    __builtin_amdgcn_global_load_lds(
        (const AS1 unsigned*)(unsigned long long)g,
        (AS3 unsigned*)(unsigned)(unsigned long long)l,
        16, 0, 0);
}

__device__ __forceinline__ unsigned pk2(float a, float b) {
    union { fp16x2 v; unsigned u; } c;
    c.v = __builtin_amdgcn_cvt_pkrtz(a, b);
    return c.u;
}

#define BAR() do { asm volatile("" ::: "memory"); __builtin_amdgcn_s_barrier(); asm volatile("" ::: "memory"); } while (0)

// ---- fused fp32 -> fp16 casts + RoPE table (one launch) ---------------------

__global__ __launch_bounds__(256) void k_cast_all(const float* __restrict__ x,
                                                  const float* __restrict__ wq,
                                                  const float* __restrict__ wo,
                                                  f16* __restrict__ Xh,
                                                  f16* __restrict__ Wqh,
                                                  f16* __restrict__ Woh,
                                                  float* __restrict__ cosT,
                                                  float* __restrict__ sinT) {
    if (blockIdx.x >= 18432) {   // RoPE table: 256 blocks x 256 thr = 65536
        int idx = (blockIdx.x - 18432) * 256 + threadIdx.x;
        int s = idx >> 5, i = idx & 31;
        float ang = (float)s * exp2f(-(float)i * 0.4152410118609190f);
        cosT[idx] = cosf(ang);
        sinT[idx] = sinf(ang);
        return;
    }
    int i = (blockIdx.x * 256 + threadIdx.x) * 4;
    const float* src; f16* dst;
    if (i < 8388608)        { src = x  + i;            dst = Xh  + i; }
    else if (i < 14680064)  { src = wq + (i - 8388608); dst = Wqh + (i - 8388608); }
    else                    { src = wo + (i - 14680064); dst = Woh + (i - 14680064); }
    float4 v = *(const float4*)src;
    union { f16 h[4]; ushort4 u; } c;
    c.h[0] = (f16)v.x; c.h[1] = (f16)v.y; c.h[2] = (f16)v.z; c.h[3] = (f16)v.w;
    *(ushort4*)dst = c.u;
}

// ---- GEMM, 256 x (64*NU) tile, 8-phase counted-vmcnt schedule --------------

template <typename OutT, int NU>
__global__ __launch_bounds__(512, 2) void k_gemm256(const f16* __restrict__ A,
                                                    const f16* __restrict__ Bt,
                                                    OutT* __restrict__ C,
                                                    int M, int N, int K) {
    constexpr int BUFSZ = 32768 + NU * 8192;
    __shared__ __align__(16) char sm[2 * BUFSZ];
    const int tid = threadIdx.x;
    const int lane = tid & 63, wid = tid >> 6;
    const int wm = wid >> 2, wn = wid & 3;          // 2 x 4 waves
    const int lr = lane & 15, g4 = lane >> 4;

    // XCD-aware swizzle (bijective: nwg % 8 == 0 for all our grids)
    const int gx = gridDim.x;
    const int nwg = gx * gridDim.y;
    int lin = blockIdx.y * gx + blockIdx.x;
    lin = (lin & 7) * (nwg >> 3) + (lin >> 3);
    const int bx = lin % gx, by = lin / gx;
    const int m0 = by * 256, n0 = bx * (64 * NU);
    const int NT = K >> 6;

    const int srow = tid >> 3;                          // 0..63
    const int scol = ((tid & 7) ^ (srow & 7)) * 8;      // halfs (pre-swizzled)
    const f16* gA = A  + (size_t)(m0 + srow) * K + scol;
    const f16* gB = Bt + (size_t)(n0 + srow) * K + scol;

    auto STGA = [&](int t, int h) {
        char* d = sm + (t & 1) * BUFSZ + h * 16384 + tid * 16;
        gload16(gA + (size_t)(h * 128) * K + t * 64,      d);
        gload16(gA + (size_t)(h * 128 + 64) * K + t * 64, d + 8192);
    };
    auto STGB = [&](int t) {
#pragma unroll
        for (int u = 0; u < NU; u++)
            gload16(gB + (size_t)(u * 64) * K + t * 64,
                    sm + (t & 1) * BUFSZ + 32768 + u * 8192 + tid * 16);
    };

    f32x4 acc[8][NU] = {};
    f16x8 bfr[NU];

    STGA(0, 0); STGA(0, 1); STGB(0);
    STGA(1, 0); STGA(1, 1); STGB(1);
    if constexpr (NU == 2) asm volatile("s_waitcnt vmcnt(6)" ::: "memory");
    else                   asm volatile("s_waitcnt vmcnt(7)" ::: "memory");
    BAR();

    for (int t = 0; t < NT; ++t) {
        const int buf = t & 1;
        const char* bA = sm + buf * BUFSZ + wm * 16384;
        const char* bB = sm + buf * BUFSZ + 32768;
        const bool sA = (t >= 1) && (t + 1 < NT);
        const bool sB = (t + 2 < NT);
#pragma unroll
        for (int p = 0; p < 4; ++p) {
            const int kk = p >> 1, mh = p & 1;
            f16x8 afr[4];
            if (mh == 0) {
#pragma unroll
                for (int n = 0; n < NU; n++) {
                    const int r = wn * (16 * NU) + n * 16 + lr;
                    bfr[n] = *(const f16x8*)(bB + ((r * 128 + kk * 64 + g4 * 16) ^ ((r & 7) << 4)));
                }
            }
#pragma unroll
            for (int i = 0; i < 4; i++) {
                const int r = (mh * 4 + i) * 16 + lr;
                afr[i] = *(const f16x8*)(bA + ((r * 128 + kk * 64 + g4 * 16) ^ ((r & 7) << 4)));
            }
            if (p == 0 && sA) STGA(t + 1, 0);
            if (p == 1 && sA) STGA(t + 1, 1);
            if (p == 3 && sB) STGB(t + 2);
            BAR();
            asm volatile("s_waitcnt lgkmcnt(0)" ::: "memory");
            __builtin_amdgcn_s_setprio(1);
#pragma unroll
            for (int i = 0; i < 4; i++)
#pragma unroll
                for (int n = 0; n < NU; n++)
                    acc[mh * 4 + i][n] = __builtin_amdgcn_mfma_f32_16x16x32_f16(afr[i], bfr[n], acc[mh * 4 + i][n], 0, 0, 0);
            __builtin_amdgcn_s_setprio(0);
            if (p == 3 && t + 1 < NT) {
                if (t + 2 < NT) {
                    if constexpr (NU == 2) asm volatile("s_waitcnt vmcnt(2)" ::: "memory");
                    else                   asm volatile("s_waitcnt vmcnt(3)" ::: "memory");
                } else {
                    asm volatile("s_waitcnt vmcnt(0)" ::: "memory");
                }
            }
            BAR();
        }
    }

#pragma unroll
    for (int m = 0; m < 8; m++)
#pragma unroll
        for (int n = 0; n < NU; n++) {
            size_t base = (size_t)(m0 + wm * 128 + m * 16 + g4 * 4) * N + (n0 + wn * (16 * NU) + n * 16 + lr);
#pragma unroll
            for (int j = 0; j < 4; j++)
                C[base + (size_t)j * N] = (OutT)acc[m][n][j];
        }
}

// ---- fused RMSNorm + RoPE + QKV split, FRAGMENT-MAJOR outputs ---------------

__global__ __launch_bounds__(256) void k_qkv_post(const f16* __restrict__ qkv,
                                                  const float* __restrict__ qg,
                                                  const float* __restrict__ kg,
                                                  const float* __restrict__ cosT,
                                                  const float* __restrict__ sinT,
                                                  f16* __restrict__ Qf,
                                                  f16* __restrict__ Kf,
                                                  f16* __restrict__ Vf) {
    __shared__ f16 tl[4][8][72];         // per-wave 8x64 transpose tile (V path)
    const int tid = threadIdx.x, lane = tid & 63, wv = tid >> 6;
    const int gw = blockIdx.x * 4 + wv;             // 0..24575
    const int b = gw / 12288;
    const int r0 = gw - b * 12288;
    const int head = r0 >> 8;                        // 0..47
    const int sblk = r0 & 255;
    const int s0 = sblk * 8;
    const int s_loc = lane >> 3, ch = lane & 7;
    const int s = s0 + s_loc;

    f16x8 v = *(const f16x8*)&qkv[((size_t)b * 2048 + s) * 3072 + head * 64 + ch * 8];

    if (head < 40) {
        float vf[8];
#pragma unroll
        for (int j = 0; j < 8; j++) vf[j] = (float)v[j];
        float ss = 0.f;
#pragma unroll
        for (int j = 0; j < 8; j++) ss += vf[j] * vf[j];
        ss += __shfl_xor(ss, 1); ss += __shfl_xor(ss, 2); ss += __shfl_xor(ss, 4);
        float rinv = rsqrtf(ss * (1.0f / 64.0f) + 1e-6f);
        const float* gam = (head < 32 ? qg : kg) + ch * 8;
        float4 g0 = *(const float4*)gam, g1 = *(const float4*)(gam + 4);
        float gv[8] = {g0.x, g0.y, g0.z, g0.w, g1.x, g1.y, g1.z, g1.w};
        float xn[8], ot[8];
#pragma unroll
        for (int j = 0; j < 8; j++) xn[j] = vf[j] * rinv * gv[j];
#pragma unroll
        for (int j = 0; j < 8; j++) ot[j] = __shfl_xor(xn[j], 4);
        const int i0 = (ch & 3) * 8;
        float4 c0  = *(const float4*)&cosT[(s << 5) + i0];
        float4 c1  = *(const float4*)&cosT[(s << 5) + i0 + 4];
        float4 sn0 = *(const float4*)&sinT[(s << 5) + i0];
        float4 sn1 = *(const float4*)&sinT[(s << 5) + i0 + 4];
        float cs[8] = {c0.x, c0.y, c0.z, c0.w, c1.x, c1.y, c1.z, c1.w};
        float sn[8] = {sn0.x, sn0.y, sn0.z, sn0.w, sn1.x, sn1.y, sn1.z, sn1.w};
        float sgn = (ch < 4) ? -1.0f : 1.0f;
        float ov[8];
#pragma unroll
        for (int j = 0; j < 8; j++) ov[j] = xn[j] * cs[j] + sgn * ot[j] * sn[j];
        if (head < 32) {
#pragma unroll
            for (int j = 0; j < 8; j++) ov[j] *= SCALE_L2E;
        }
        uint4 o;
        o.x = pk2(ov[0], ov[1]); o.y = pk2(ov[2], ov[3]);
        o.z = pk2(ov[4], ov[5]); o.w = pk2(ov[6], ov[7]);
        const int t = s >> 5;
        const int lane2 = (s & 31) + ((ch & 1) << 5);
        const int c = ch >> 1;
        f16* dst = (head < 32)
            ? Qf + (((size_t)(b * 32 + head) * 256 + t * 4 + c) * 512 + lane2 * 8)
            : Kf + (((size_t)(b * 8 + head - 32) * 256 + t * 4 + c) * 512 + lane2 * 8);
        *(uint4*)dst = o;
    } else {
        const int kh = head - 40;
        *(f16x8*)&tl[wv][s_loc][ch * 8] = v;
        asm volatile("s_waitcnt lgkmcnt(0)" ::: "memory");
        f16x8 cv;
#pragma unroll
        for (int rr = 0; rr < 8; rr++) cv[rr] = tl[wv][rr][lane];
        const int d = lane, dh = d >> 5;
        const int t = s0 >> 5, c = (s0 >> 4) & 1, hv = (s0 >> 3) & 1;
        const int g = dh * 2 + c;
        f16* dst = Vf + (((size_t)(b * 8 + kh) * 256 + t * 4 + g) * 512
                         + ((d & 31) + (hv << 5)) * 8);
        *(f16x8*)dst = cv;
    }
}

// ---- flash attention, causal, GQA, 4-wave KV-shared blocks ------------------
// Block = 4 waves; wave w owns q-block g*4+w of one (b,h). K/V tiles staged
// ONCE per block into double-buffered LDS (global_load_lds, linear layout) and
// consumed by all 4 waves -> global K/V traffic / 4. FIXED-SHIFT softmax.
// Sessions pair group g with 15-g: every block processes exactly 68 tiles.
// Ledger per tile t: compute(t) from kv[t&1]; BAR; stage(t+2) into kv[t&1];
// vmcnt(2) [keeps only stage(t+2) in flight => stage(t+1) landed]; BAR.

__global__ __launch_bounds__(256) void k_attn(const f16* __restrict__ Qf,
                                              const f16* __restrict__ Kf,
                                              const f16* __restrict__ Vf,
                                              f16* __restrict__ ctx) {
    __shared__ __align__(16) char kv[2][8192];    // [buf][K 4KB | V 4KB]
    const int tid = threadIdx.x, lane = tid & 63, w = tid >> 6;
    const int lq = lane & 31, hi = lane >> 5;
    const int bh = blockIdx.y, b = bh >> 5, h = bh & 31, kh = h >> 2;

    const f16* Qfp = Qf + (size_t)(b * 32 + h) * 131072;
    const f16* Kfp = Kf + (size_t)(b * 8 + kh) * 131072;
    const f16* Vfp = Vf + (size_t)(b * 8 + kh) * 131072;
    f16*       ctxbase = ctx + (size_t)b * 2048 * 2048 + h * 64;

#pragma unroll
    for (int s = 0; s < 2; s++) {
        const int g  = s == 0 ? (int)blockIdx.x : 15 - (int)blockIdx.x;
        const int qb = g * 4 + w;
        const int nt = g * 4 + 4;

        f16x8 qf[4];
#pragma unroll
        for (int c = 0; c < 4; c++)
            qf[c] = *(const f16x8*)&Qfp[((size_t)qb * 4 + c) * 512 + lane * 8];

        f32x16 o0 = {}, o1 = {};
        float lrun = 0.0f;

        auto STAGE = [&](int t) {
            gload16(Kfp + (size_t)t * 2048 + tid * 8, kv[t & 1] + tid * 16);
            gload16(Vfp + (size_t)t * 2048 + tid * 8, kv[t & 1] + 4096 + tid * 16);
        };

        STAGE(0); STAGE(1);
        asm volatile("s_waitcnt vmcnt(2)" ::: "memory");
        BAR();

        for (int t = 0; t < nt; ++t) {
            const char* bufp = kv[t & 1];
            if (t <= qb) {
                f16x8 kfr[4];
#pragma unroll
                for (int c = 0; c < 4; c++)
                    kfr[c] = *(const f16x8*)(bufp + c * 1024 + lane * 16);
                f32x16 st = {};
#pragma unroll
                for (int c = 0; c < 4; c++)
                    st = __builtin_amdgcn_mfma_f32_32x32x16_f16(kfr[c], qf[c], st, 0, 0, 0);

                f16x8 va[2], vb[2];
#pragma unroll
                for (int c = 0; c < 2; c++) {
                    va[c] = *(const f16x8*)(bufp + 4096 + c * 1024 + lane * 16);
                    vb[c] = *(const f16x8*)(bufp + 4096 + (2 + c) * 1024 + lane * 16);
                }

                if (t == qb) {
#pragma unroll
                    for (int r = 0; r < 16; r++) {
                        int kvl = (r & 3) + ((r >> 2) << 3) + (hi << 2);
                        if (kvl > lq) st[r] = -1e30f;
                    }
                }

                unsigned X[8];
                float ps0 = 0.0f, ps1 = 0.0f;
#pragma unroll
                for (int j = 0; j < 8; j++) {
                    float p0 = __builtin_amdgcn_exp2f(st[2 * j]);
                    float p1 = __builtin_amdgcn_exp2f(st[2 * j + 1]);
                    ps0 += p0; ps1 += p1;
                    X[j] = pk2(p0, p1);
                }
                lrun += ps0 + ps1;

#pragma unroll
                for (int c = 0; c < 2; c++) {
                    unsigned a0 = X[4 * c], a1 = X[4 * c + 1], a2 = X[4 * c + 2], a3 = X[4 * c + 3];
                    asm volatile("v_permlane32_swap_b32 %0, %1" : "+v"(a0), "+v"(a2));
                    asm volatile("v_permlane32_swap_b32 %0, %1" : "+v"(a1), "+v"(a3));
                    union { unsigned u[4]; f16x8 v; } pb;
                    pb.u[0] = a0; pb.u[1] = a1; pb.u[2] = a2; pb.u[3] = a3;
                    o0 = __builtin_amdgcn_mfma_f32_32x32x16_f16(va[c], pb.v, o0, 0, 0, 0);
                    o1 = __builtin_amdgcn_mfma_f32_32x32x16_f16(vb[c], pb.v, o1, 0, 0, 0);
                }
            }
            BAR();                               // all waves done reading kv[t&1]
            if (t + 2 < nt) {
                STAGE(t + 2);                    // overwrite kv[t&1]
                asm volatile("s_waitcnt vmcnt(2)" ::: "memory");
            } else if (t + 1 < nt) {
                asm volatile("s_waitcnt vmcnt(0)" ::: "memory");
            }
            BAR();                               // kv[(t+1)&1] ready for all
        }

        float lt  = lrun + __shfl_xor(lrun, 32);
        float inv = 1.0f / lt;
        unsigned* row = (unsigned*)(ctxbase + (size_t)(qb * 32 + lq) * 2048);
#pragma unroll
        for (int gg = 0; gg < 4; gg++) {
            uint2 a, e;
            a.x = pk2(o0[4 * gg]     * inv, o0[4 * gg + 1] * inv);
            a.y = pk2(o0[4 * gg + 2] * inv, o0[4 * gg + 3] * inv);
            *(uint2*)(row + 2 * hi + 4 * gg) = a;
            e.x = pk2(o1[4 * gg]     * inv, o1[4 * gg + 1] * inv);
            e.y = pk2(o1[4 * gg + 2] * inv, o1[4 * gg + 3] * inv);
            *(uint2*)(row + 16 + 2 * hi + 4 * gg) = e;
        }
    }
}

// ---- launcher ---------------------------------------------------------------

extern "C" void kernel_launch(void* const* d_in, const int* in_sizes, int n_in,
                              void* d_out, int out_size, void* d_ws, size_t ws_size,
                              hipStream_t stream) {
    const float* x     = (const float*)d_in[0];
    const float* w_qkv = (const float*)d_in[1];
    const float* w_out = (const float*)d_in[2];
    const float* qg    = (const float*)d_in[3];
    const float* kg    = (const float*)d_in[4];
    float* out = (float*)d_out;
    char* ws = (char*)d_ws;

    float* cosT = (float*)(ws);
    float* sinT = (float*)(ws + 262144);
    f16* Xh     = (f16*)(ws + 524288);
    f16* Wqkvh  = (f16*)(ws + 17301504);
    f16* Wouth  = (f16*)(ws + 29884416);
    f16* QKVh   = (f16*)(ws + 38273024);
    f16* Qfb    = (f16*)(ws + 63438848);    // fragment-major Q (pre-scaled), 16 MB
    f16* Kfb    = (f16*)(ws + 80216064);    // fragment-major K, 4 MB
    f16* Vfb    = (f16*)(ws + 84410368);    // fragment-major V, 4 MB
    f16* Ctxh   = (f16*)(ws + 88604672);

    k_cast_all<<<18688, 256, 0, stream>>>(x, w_qkv, w_out, Xh, Wqkvh, Wouth, cosT, sinT);

    // qkv = x @ w_qkv^T : M=4096, N=3072, K=2048  (256x192 tile, 256 blocks)
    k_gemm256<f16, 3><<<dim3(16, 16), 512, 0, stream>>>(Xh, Wqkvh, QKVh, 4096, 3072, 2048);

    // fragment-major post-process: 24576 waves / 4 per block
    k_qkv_post<<<6144, 256, 0, stream>>>(QKVh, qg, kg, cosT, sinT, Qfb, Kfb, Vfb);

    // attention: 512 blocks x 4 waves, KV staged in LDS, shared across waves
    k_attn<<<dim3(8, 64), 256, 0, stream>>>(Qfb, Kfb, Vfb, Ctxh);

    // out = ctx @ w_out^T : M=4096, N=2048, K=2048  (256x128 tile, 256 blocks)
    k_gemm256<float, 2><<<dim3(16, 16), 512, 0, stream>>>(Ctxh, Wouth, out, 4096, 2048, 2048);
}